// Round 10
// baseline (370.373 us; speedup 1.0000x reference)
//
#include <hip/hip_runtime.h>
#include <hip/hip_bf16.h>

#define NODELEN 394
#define IN_DIM 788
#define H2DIM 192
#define EMBDIM 128
#define NCHUNK 197   // 394 elems = 197 x (float2 | uint-packed-bf16x2)

typedef __attribute__((ext_vector_type(4))) float f32x4;
typedef __attribute__((ext_vector_type(8))) short bfrag;  // 8 bf16 = 4 VGPRs

// raw barrier: LDS-coherent (ds_write completion tracked by lgkmcnt), does NOT
// drain vmcnt -- global prefetches stay in flight across the barrier.
#define LBAR() do { asm volatile("s_waitcnt lgkmcnt(0)" ::: "memory"); \
                    __builtin_amdgcn_s_barrier(); } while (0)

static __device__ __forceinline__ unsigned short f2bf(float f) {
    union { float f; unsigned u; } v; v.f = f;
    unsigned r = v.u + 0x7FFFu + ((v.u >> 16) & 1u);  // round-to-nearest-even
    return (unsigned short)(r >> 16);
}
static __device__ __forceinline__ float bf2f(unsigned short h) {
    union { unsigned u; float f; } v; v.u = ((unsigned)h) << 16;
    return v.f;
}
static __device__ __forceinline__ unsigned short f2bf_fast(float f) {
    __hip_bfloat16 h = __float2bfloat16(f);
    union { __hip_bfloat16 h; unsigned short u; } c; c.h = h; return c.u;
}

// ---------------- CSR build ----------------

__global__ void count_deg(const int* __restrict__ dst, int* __restrict__ deg, int e) {
    int i = blockIdx.x * blockDim.x + threadIdx.x;
    if (i < e) atomicAdd(&deg[dst[i]], 1);
}

__global__ void block_sum(const int* __restrict__ deg, int* __restrict__ bsum, int n) {
    __shared__ int s[256];
    int t = threadIdx.x;
    int i = blockIdx.x * 256 + t;
    s[t] = (i < n) ? deg[i] : 0;
    __syncthreads();
    for (int d = 128; d > 0; d >>= 1) {
        if (t < d) s[t] += s[t + d];
        __syncthreads();
    }
    if (t == 0) bsum[blockIdx.x] = s[0];
}

__global__ void scan_bsums(int* bsum, int nb) {
    __shared__ int s[256];
    int t = threadIdx.x;
    int x0 = (t < nb) ? bsum[t] : 0;
    s[t] = x0;
    __syncthreads();
    for (int d = 1; d < 256; d <<= 1) {
        int u = (t >= d) ? s[t - d] : 0;
        __syncthreads();
        s[t] += u;
        __syncthreads();
    }
    if (t < nb) bsum[t] = s[t] - x0;
}

__global__ void block_scan(const int* __restrict__ deg, const int* __restrict__ boff,
                           int* __restrict__ rowstart, int* __restrict__ cursor,
                           float* __restrict__ inv, int n) {
    __shared__ int s[256];
    int t = threadIdx.x;
    int i = blockIdx.x * 256 + t;
    int x0 = (i < n) ? deg[i] : 0;
    s[t] = x0;
    __syncthreads();
    for (int d = 1; d < 256; d <<= 1) {
        int u = (t >= d) ? s[t - d] : 0;
        __syncthreads();
        s[t] += u;
        __syncthreads();
    }
    if (i < n) {
        int r = boff[blockIdx.x] + s[t] - x0;
        rowstart[i] = r;
        cursor[i] = r;
        inv[i] = 1.0f / fmaxf((float)x0, 1.0f);
    }
}

__global__ void fill_edges(const int* __restrict__ src, const int* __restrict__ dst,
                           int* __restrict__ cursor, int* __restrict__ elist, int e) {
    int i = blockIdx.x * blockDim.x + threadIdx.x;
    if (i < e) {
        int p = atomicAdd(&cursor[dst[i]], 1);
        elist[p] = src[i];
    }
}

// ---------------- aggregation (gather, flat-indexed: 100% lane utilization) ------

__global__ __launch_bounds__(256) void gather1(
        const float* __restrict__ feat, const int* __restrict__ rowstart,
        const int* __restrict__ deg, const float* __restrict__ inv,
        const int* __restrict__ elist, unsigned short* __restrict__ h1, int total) {
    for (int idx = blockIdx.x * 256 + threadIdx.x; idx < total; idx += gridDim.x * 256) {
        const int node = idx / NCHUNK;
        const int c = idx - node * NCHUNK;
        const int beg = rowstart[node];
        const int dc = deg[node];
        const float s = inv[node];
        const size_t off = (size_t)c * 2;

        float ax = 0.f, ay = 0.f, bx = 0.f, by = 0.f;
        float cx = 0.f, cy = 0.f, dx = 0.f, dy = 0.f;
        int j = 0;
        for (; j + 3 < dc; j += 4) {
            int n0 = elist[beg + j], n1 = elist[beg + j + 1];
            int n2 = elist[beg + j + 2], n3 = elist[beg + j + 3];
            float2 v0 = *(const float2*)(feat + (size_t)n0 * NODELEN + off);
            float2 v1 = *(const float2*)(feat + (size_t)n1 * NODELEN + off);
            float2 v2 = *(const float2*)(feat + (size_t)n2 * NODELEN + off);
            float2 v3 = *(const float2*)(feat + (size_t)n3 * NODELEN + off);
            ax += v0.x; ay += v0.y; bx += v1.x; by += v1.y;
            cx += v2.x; cy += v2.y; dx += v3.x; dy += v3.y;
        }
        for (; j < dc; ++j) {
            int n0 = elist[beg + j];
            float2 v0 = *(const float2*)(feat + (size_t)n0 * NODELEN + off);
            ax += v0.x; ay += v0.y;
        }
        float fx = (ax + bx + cx + dx) * s;
        float fy = (ay + by + cy + dy) * s;
        if (c == 0) fx = 0.f;
        unsigned out = ((unsigned)f2bf(fy) << 16) | (unsigned)f2bf(fx);
        *(unsigned*)(h1 + (size_t)node * NODELEN + off) = out;
    }
}

// emb fp32 [n][788]; optionally emb16 bf16 [n][800] (cols 788..799 zero)
__global__ __launch_bounds__(256) void gather2_emb(
        const float* __restrict__ feat, const unsigned* __restrict__ h1,
        const int* __restrict__ rowstart, const int* __restrict__ deg,
        const float* __restrict__ inv, const int* __restrict__ elist,
        float* __restrict__ emb, unsigned* __restrict__ emb16u, int total) {
    for (int idx = blockIdx.x * 256 + threadIdx.x; idx < total; idx += gridDim.x * 256) {
        const int node = idx / NCHUNK;
        const int c = idx - node * NCHUNK;
        const int beg = rowstart[node];
        const int dc = deg[node];
        const float s = inv[node];

        float ax = 0.f, ay = 0.f, bx = 0.f, by = 0.f;
        float cx = 0.f, cy = 0.f, dx = 0.f, dy = 0.f;
        int j = 0;
        for (; j + 3 < dc; j += 4) {
            int n0 = elist[beg + j], n1 = elist[beg + j + 1];
            int n2 = elist[beg + j + 2], n3 = elist[beg + j + 3];
            unsigned u0 = h1[(size_t)n0 * NCHUNK + c];
            unsigned u1 = h1[(size_t)n1 * NCHUNK + c];
            unsigned u2 = h1[(size_t)n2 * NCHUNK + c];
            unsigned u3 = h1[(size_t)n3 * NCHUNK + c];
            ax += bf2f((unsigned short)u0); ay += bf2f((unsigned short)(u0 >> 16));
            bx += bf2f((unsigned short)u1); by += bf2f((unsigned short)(u1 >> 16));
            cx += bf2f((unsigned short)u2); cy += bf2f((unsigned short)(u2 >> 16));
            dx += bf2f((unsigned short)u3); dy += bf2f((unsigned short)(u3 >> 16));
        }
        for (; j < dc; ++j) {
            int n0 = elist[beg + j];
            unsigned u0 = h1[(size_t)n0 * NCHUNK + c];
            ax += bf2f((unsigned short)u0); ay += bf2f((unsigned short)(u0 >> 16));
        }
        float hx = (ax + bx + cx + dx) * s;
        float hy = (ay + by + cy + dy) * s;

        const float* fr = feat + (size_t)node * NODELEN;
        float* er = emb + (size_t)node * IN_DIM;
        float2 fv = *(const float2*)(fr + c * 2);
        if (c == 0) { fv.x = 0.f; hx = 0.f; }
        *(float2*)(er + c * 2) = fv;
        float2 hv; hv.x = hx; hv.y = hy;
        *(float2*)(er + NODELEN + c * 2) = hv;

        if (emb16u) {
            unsigned* e16 = emb16u + (size_t)node * 400;
            e16[c]          = ((unsigned)f2bf(fv.y) << 16) | (unsigned)f2bf(fv.x);
            e16[NCHUNK + c] = ((unsigned)f2bf(hy)  << 16) | (unsigned)f2bf(hx);
            if (c < 6) e16[394 + c] = 0u;
        }
    }
}

// ---------------- fused weight pre-transpose ----------
__device__ __forceinline__ void tr_one(const float* W, unsigned short* Wt,
                                       int K, int N, int Kp, int idx) {
    int nrow = idx / Kp, k = idx - nrow * Kp;
    Wt[idx] = (k < K) ? f2bf(W[(size_t)k * N + nrow]) : (unsigned short)0;
}

#define T1E (192 * 800)
#define T2E (128 * 192)
#define T3E (192 * 128)
#define T4E (788 * 192)

__global__ void transpose_all(const float* __restrict__ W1, unsigned short* __restrict__ Wt1,
                              const float* __restrict__ W2, unsigned short* __restrict__ Wt2,
                              const float* __restrict__ W3, unsigned short* __restrict__ Wt3,
                              const float* __restrict__ W4, unsigned short* __restrict__ Wt4) {
    int idx = blockIdx.x * 256 + threadIdx.x;
    if (idx < T1E) { tr_one(W1, Wt1, IN_DIM, H2DIM, 800, idx); return; }
    idx -= T1E;
    if (idx < T2E) { tr_one(W2, Wt2, H2DIM, EMBDIM, 192, idx); return; }
    idx -= T2E;
    if (idx < T3E) { tr_one(W3, Wt3, EMBDIM, H2DIM, 128, idx); return; }
    idx -= T3E;
    if (idx < T4E) { tr_one(W4, Wt4, H2DIM, IN_DIM, 192, idx); return; }
}

// ---------------- MLP kernels: BM=128, 2-deep prefetch pipeline ------------------
static __device__ __forceinline__ int bs_addr(int r, int s) {           // Bs[192][32]
    return r * 32 + ((s ^ ((r >> 1) & 3)) << 3);
}
static __device__ __forceinline__ int xy_base(int r, int s) {           // XY[128][192]
    int ph = (s & 24) | ((s ^ r) & 7);
    return r * 192 + (ph << 3);
}
static __device__ __forceinline__ int xy_addr_s(int r, int col) { return xy_base(r, col >> 3) + (col & 7); }

static __device__ __forceinline__ bfrag load_af_bf(const unsigned short* A800, int gm, int M, int col) {
    const bfrag zf = {0, 0, 0, 0, 0, 0, 0, 0};
    return (gm < M) ? *(const bfrag*)(A800 + (size_t)gm * 800 + col) : zf;
}
static __device__ __forceinline__ bfrag load_af_f32(const float* A, int gm, int M, int col) {
    float t[8];
    #pragma unroll
    for (int q = 0; q < 8; ++q) t[q] = 0.f;
    if (gm < M) {
        const float* rp = A + (size_t)gm * IN_DIM;
        if (col + 8 <= IN_DIM) {
            float4 v0 = *(const float4*)(rp + col), v1 = *(const float4*)(rp + col + 4);
            t[0] = v0.x; t[1] = v0.y; t[2] = v0.z; t[3] = v0.w;
            t[4] = v1.x; t[5] = v1.y; t[6] = v1.z; t[7] = v1.w;
        } else {
            #pragma unroll
            for (int q = 0; q < 8; ++q) if (col + q < IN_DIM) t[q] = rp[col + q];
        }
    }
    union { unsigned short u[8]; bfrag v; } pk;
    #pragma unroll
    for (int q = 0; q < 8; ++q) pk.u[q] = f2bf_fast(t[q]);
    return pk.v;
}

// ===== kernel A: stage1+2  emb -> x(lds) -> encoded(f32) + enc16(bf16) ==========
template <int ABF>
__global__ __launch_bounds__(256, 2) void mlp12(
    const void* __restrict__ Aemb,           // ABF ? bf16[n][800] : f32[n][788]
    const unsigned short* __restrict__ Wt1,  // [192][800]
    const unsigned short* __restrict__ Wt2,  // [128][192]
    const float* __restrict__ b1, const float* __restrict__ b2,
    float* __restrict__ encoded, unsigned short* __restrict__ enc16, int M)
{
    __shared__ unsigned short XY[128 * 192];     // 48 KB
    __shared__ unsigned short Bs[2][192 * 32];   // 24 KB

    const int tid = threadIdx.x;
    const int wid = tid >> 6, l = tid & 63;
    const int wm = wid >> 1, wn = wid & 1;       // 2x2 waves; wave tile 64 x 96
    const int lr = l & 15, lk = l >> 4;
    const int m0 = blockIdx.x * 128;

    const int r0 = tid >> 2, s0 = tid & 3;       // staging units
    const int r1 = r0 + 64, r2 = r0 + 128;
    const int bw0 = bs_addr(r0, s0);
    const int bw1 = bs_addr(r1, s0);
    const int bw2 = bs_addr(r2, s0);
    int brd6[6], brd4[4];
    #pragma unroll
    for (int j = 0; j < 6; ++j) brd6[j] = bs_addr(wn * 96 + j * 16 + lr, lk);
    #pragma unroll
    for (int j = 0; j < 4; ++j) brd4[j] = bs_addr(wn * 64 + j * 16 + lr, lk);

    int gmA[4];
    #pragma unroll
    for (int i = 0; i < 4; ++i) gmA[i] = m0 + wm * 64 + i * 16 + lr;

    // ---- STAGE 1: K=800 (25 steps), N=192, 2-deep prefetch ----
    {
        f32x4 acc[4][6];
        #pragma unroll
        for (int i = 0; i < 4; ++i)
            #pragma unroll
            for (int j = 0; j < 6; ++j) acc[i][j] = (f32x4){0.f, 0.f, 0.f, 0.f};

        bfrag afC[4], afN[4], afN2[4], bR1[3], bR2[3];
        #pragma unroll
        for (int i = 0; i < 4; ++i) {
            afC[i] = ABF ? load_af_bf((const unsigned short*)Aemb, gmA[i], M, lk * 8)
                         : load_af_f32((const float*)Aemb, gmA[i], M, lk * 8);
            afN[i] = ABF ? load_af_bf((const unsigned short*)Aemb, gmA[i], M, 32 + lk * 8)
                         : load_af_f32((const float*)Aemb, gmA[i], M, 32 + lk * 8);
        }
        // B(0) -> Bs[0]; B(1) -> regs
        *(bfrag*)&Bs[0][bw0] = *(const bfrag*)(Wt1 + (size_t)r0 * 800 + s0 * 8);
        *(bfrag*)&Bs[0][bw1] = *(const bfrag*)(Wt1 + (size_t)r1 * 800 + s0 * 8);
        *(bfrag*)&Bs[0][bw2] = *(const bfrag*)(Wt1 + (size_t)r2 * 800 + s0 * 8);
        bR1[0] = *(const bfrag*)(Wt1 + (size_t)r0 * 800 + 32 + s0 * 8);
        bR1[1] = *(const bfrag*)(Wt1 + (size_t)r1 * 800 + 32 + s0 * 8);
        bR1[2] = *(const bfrag*)(Wt1 + (size_t)r2 * 800 + 32 + s0 * 8);
        LBAR();

        #pragma unroll 5
        for (int kt = 0; kt < 25; ++kt) {
            if (kt < 23) {
                int k2 = (kt + 2) * 32;
                #pragma unroll
                for (int i = 0; i < 4; ++i)
                    afN2[i] = ABF ? load_af_bf((const unsigned short*)Aemb, gmA[i], M, k2 + lk * 8)
                                  : load_af_f32((const float*)Aemb, gmA[i], M, k2 + lk * 8);
                bR2[0] = *(const bfrag*)(Wt1 + (size_t)r0 * 800 + k2 + s0 * 8);
                bR2[1] = *(const bfrag*)(Wt1 + (size_t)r1 * 800 + k2 + s0 * 8);
                bR2[2] = *(const bfrag*)(Wt1 + (size_t)r2 * 800 + k2 + s0 * 8);
            }
            const unsigned short* B = Bs[kt & 1];
            bfrag bf[6];
            #pragma unroll
            for (int j = 0; j < 6; ++j) bf[j] = *(const bfrag*)&B[brd6[j]];
            #pragma unroll
            for (int i = 0; i < 4; ++i)
                #pragma unroll
                for (int j = 0; j < 6; ++j)
                    acc[i][j] = __builtin_amdgcn_mfma_f32_16x16x32_bf16(afC[i], bf[j], acc[i][j], 0, 0, 0);
            if (kt < 24) {
                unsigned short* Bn = Bs[(kt + 1) & 1];
                *(bfrag*)&Bn[bw0] = bR1[0];
                *(bfrag*)&Bn[bw1] = bR1[1];
                *(bfrag*)&Bn[bw2] = bR1[2];
                LBAR();
                #pragma unroll
                for (int i = 0; i < 4; ++i) { afC[i] = afN[i]; afN[i] = afN2[i]; }
                bR1[0] = bR2[0]; bR1[1] = bR2[1]; bR1[2] = bR2[2];
            }
        }
        float bv[6];
        #pragma unroll
        for (int j = 0; j < 6; ++j) bv[j] = b1[wn * 96 + j * 16 + lr];
        #pragma unroll
        for (int i = 0; i < 4; ++i)
            #pragma unroll
            for (int j = 0; j < 6; ++j)
                #pragma unroll
                for (int r = 0; r < 4; ++r) {
                    int m = wm * 64 + i * 16 + lk * 4 + r;
                    int n1 = wn * 96 + j * 16 + lr;
                    XY[xy_addr_s(m, n1)] = f2bf_fast(fmaxf(acc[i][j][r] + bv[j], 0.f));
                }
    }
    __syncthreads();   // x visible, stage-1 Bs reads done

    // ---- STAGE 2: K=192 (6 steps), N=128, 2-deep B ----
    {
        f32x4 acc[4][4];
        #pragma unroll
        for (int i = 0; i < 4; ++i)
            #pragma unroll
            for (int j = 0; j < 4; ++j) acc[i][j] = (f32x4){0.f, 0.f, 0.f, 0.f};

        bfrag bR1[2], bR2[2];
        *(bfrag*)&Bs[0][bw0] = *(const bfrag*)(Wt2 + (size_t)r0 * 192 + s0 * 8);
        *(bfrag*)&Bs[0][bw1] = *(const bfrag*)(Wt2 + (size_t)r1 * 192 + s0 * 8);
        bR1[0] = *(const bfrag*)(Wt2 + (size_t)r0 * 192 + 32 + s0 * 8);
        bR1[1] = *(const bfrag*)(Wt2 + (size_t)r1 * 192 + 32 + s0 * 8);
        LBAR();

        #pragma unroll
        for (int kt = 0; kt < 6; ++kt) {
            if (kt < 4) {
                int k2 = (kt + 2) * 32;
                bR2[0] = *(const bfrag*)(Wt2 + (size_t)r0 * 192 + k2 + s0 * 8);
                bR2[1] = *(const bfrag*)(Wt2 + (size_t)r1 * 192 + k2 + s0 * 8);
            }
            const unsigned short* B = Bs[kt & 1];
            bfrag af[4], bf[4];
            #pragma unroll
            for (int i = 0; i < 4; ++i)
                af[i] = *(const bfrag*)&XY[xy_base(wm * 64 + i * 16 + lr, kt * 4 + lk)];
            #pragma unroll
            for (int j = 0; j < 4; ++j) bf[j] = *(const bfrag*)&B[brd4[j]];
            #pragma unroll
            for (int i = 0; i < 4; ++i)
                #pragma unroll
                for (int j = 0; j < 4; ++j)
                    acc[i][j] = __builtin_amdgcn_mfma_f32_16x16x32_bf16(af[i], bf[j], acc[i][j], 0, 0, 0);
            if (kt < 5) {
                unsigned short* Bn = Bs[(kt + 1) & 1];
                *(bfrag*)&Bn[bw0] = bR1[0];
                *(bfrag*)&Bn[bw1] = bR1[1];
                LBAR();
                bR1[0] = bR2[0]; bR1[1] = bR2[1];
            }
        }

        float bv[4];
        #pragma unroll
        for (int j = 0; j < 4; ++j) bv[j] = b2[wn * 64 + j * 16 + lr];
        #pragma unroll
        for (int i = 0; i < 4; ++i)
            #pragma unroll
            for (int j = 0; j < 4; ++j)
                #pragma unroll
                for (int r = 0; r < 4; ++r) {
                    int m = wm * 64 + i * 16 + lk * 4 + r;
                    int nn = wn * 64 + j * 16 + lr;
                    float v = acc[i][j][r] + bv[j];
                    int gm = m0 + m;
                    if (gm < M) {
                        encoded[(size_t)gm * EMBDIM + nn] = v;
                        enc16[(size_t)gm * EMBDIM + nn] = f2bf_fast(v);
                    }
                }
    }
}

// ===== kernel B: stage3+4  enc16 -> y(lds) -> decoded(f32) ======================
__global__ __launch_bounds__(256, 2) void mlp34(
    const unsigned short* __restrict__ enc16,
    const unsigned short* __restrict__ Wt3,  // [192][128]
    const unsigned short* __restrict__ Wt4,  // [788][192]
    const float* __restrict__ b3, const float* __restrict__ b4,
    float* __restrict__ decoded, int M)
{
    __shared__ unsigned short XY[128 * 192];     // 48 KB (y)
    __shared__ unsigned short Bs[2][192 * 32];   // 24 KB

    const int tid = threadIdx.x;
    const int wid = tid >> 6, l = tid & 63;
    const int wm = wid >> 1, wn = wid & 1;
    const int lr = l & 15, lk = l >> 4;
    const int m0 = blockIdx.x * 128;
    const bfrag zf = {0, 0, 0, 0, 0, 0, 0, 0};

    const int r0 = tid >> 2, s0 = tid & 3;
    const int r1 = r0 + 64, r2 = r0 + 128;
    const int bw0 = bs_addr(r0, s0);
    const int bw1 = bs_addr(r1, s0);
    const int bw2 = bs_addr(r2, s0);
    int brd6[6], brd4[4];
    #pragma unroll
    for (int j = 0; j < 6; ++j) brd6[j] = bs_addr(wn * 96 + j * 16 + lr, lk);
    #pragma unroll
    for (int j = 0; j < 4; ++j) brd4[j] = bs_addr(wn * 64 + j * 16 + lr, lk);

    int gmA[4];
    #pragma unroll
    for (int i = 0; i < 4; ++i) gmA[i] = m0 + wm * 64 + i * 16 + lr;

    // ---- STAGE 3: y = relu(enc @ W3 + b3), K=128 (4 steps), N=192, 2-deep ----
    {
        f32x4 acc[4][6];
        #pragma unroll
        for (int i = 0; i < 4; ++i)
            #pragma unroll
            for (int j = 0; j < 6; ++j) acc[i][j] = (f32x4){0.f, 0.f, 0.f, 0.f};

        bfrag afC[4], afN[4], afN2[4], bR1[3], bR2[3];
        #pragma unroll
        for (int i = 0; i < 4; ++i) {
            afC[i] = (gmA[i] < M) ? *(const bfrag*)(enc16 + (size_t)gmA[i] * EMBDIM + lk * 8) : zf;
            afN[i] = (gmA[i] < M) ? *(const bfrag*)(enc16 + (size_t)gmA[i] * EMBDIM + 32 + lk * 8) : zf;
        }
        *(bfrag*)&Bs[0][bw0] = *(const bfrag*)(Wt3 + (size_t)r0 * 128 + s0 * 8);
        *(bfrag*)&Bs[0][bw1] = *(const bfrag*)(Wt3 + (size_t)r1 * 128 + s0 * 8);
        *(bfrag*)&Bs[0][bw2] = *(const bfrag*)(Wt3 + (size_t)r2 * 128 + s0 * 8);
        bR1[0] = *(const bfrag*)(Wt3 + (size_t)r0 * 128 + 32 + s0 * 8);
        bR1[1] = *(const bfrag*)(Wt3 + (size_t)r1 * 128 + 32 + s0 * 8);
        bR1[2] = *(const bfrag*)(Wt3 + (size_t)r2 * 128 + 32 + s0 * 8);
        LBAR();

        #pragma unroll
        for (int kt = 0; kt < 4; ++kt) {
            if (kt < 2) {
                int k2 = (kt + 2) * 32;
                #pragma unroll
                for (int i = 0; i < 4; ++i)
                    afN2[i] = (gmA[i] < M)
                        ? *(const bfrag*)(enc16 + (size_t)gmA[i] * EMBDIM + k2 + lk * 8) : zf;
                bR2[0] = *(const bfrag*)(Wt3 + (size_t)r0 * 128 + k2 + s0 * 8);
                bR2[1] = *(const bfrag*)(Wt3 + (size_t)r1 * 128 + k2 + s0 * 8);
                bR2[2] = *(const bfrag*)(Wt3 + (size_t)r2 * 128 + k2 + s0 * 8);
            }
            const unsigned short* B = Bs[kt & 1];
            bfrag bf[6];
            #pragma unroll
            for (int j = 0; j < 6; ++j) bf[j] = *(const bfrag*)&B[brd6[j]];
            #pragma unroll
            for (int i = 0; i < 4; ++i)
                #pragma unroll
                for (int j = 0; j < 6; ++j)
                    acc[i][j] = __builtin_amdgcn_mfma_f32_16x16x32_bf16(afC[i], bf[j], acc[i][j], 0, 0, 0);
            if (kt < 3) {
                unsigned short* Bn = Bs[(kt + 1) & 1];
                *(bfrag*)&Bn[bw0] = bR1[0];
                *(bfrag*)&Bn[bw1] = bR1[1];
                *(bfrag*)&Bn[bw2] = bR1[2];
                LBAR();
                #pragma unroll
                for (int i = 0; i < 4; ++i) { afC[i] = afN[i]; afN[i] = afN2[i]; }
                bR1[0] = bR2[0]; bR1[1] = bR2[1]; bR1[2] = bR2[2];
            }
        }

        float bv[6];
        #pragma unroll
        for (int j = 0; j < 6; ++j) bv[j] = b3[wn * 96 + j * 16 + lr];
        #pragma unroll
        for (int i = 0; i < 4; ++i)
            #pragma unroll
            for (int j = 0; j < 6; ++j)
                #pragma unroll
                for (int r = 0; r < 4; ++r) {
                    int m = wm * 64 + i * 16 + lk * 4 + r;
                    int nc = wn * 96 + j * 16 + lr;
                    XY[xy_addr_s(m, nc)] = f2bf_fast(fmaxf(acc[i][j][r] + bv[j], 0.f));
                }
    }
    __syncthreads();   // y visible

    // ---- STAGE 4: dec = y @ W4 + b4, K=192 (6 steps), N=788 (7 x 128), 2-deep ----
    {
        bfrag af4[6][4];   // hoisted once, reused across chunks
        #pragma unroll
        for (int q = 0; q < 6; ++q)
            #pragma unroll
            for (int i = 0; i < 4; ++i)
                af4[q][i] = *(const bfrag*)&XY[xy_base(wm * 64 + i * 16 + lr, q * 4 + lk)];

        bfrag bR1[2], bR2[2];
        // t=0 -> Bs[0]; t=1 -> regs (rows < 788 for chunk 0)
        *(bfrag*)&Bs[0][bw0] = *(const bfrag*)(Wt4 + (size_t)r0 * 192 + s0 * 8);
        *(bfrag*)&Bs[0][bw1] = *(const bfrag*)(Wt4 + (size_t)r1 * 192 + s0 * 8);
        bR1[0] = *(const bfrag*)(Wt4 + (size_t)r0 * 192 + 32 + s0 * 8);
        bR1[1] = *(const bfrag*)(Wt4 + (size_t)r1 * 192 + 32 + s0 * 8);
        LBAR();

        for (int nc = 0; nc < 7; ++nc) {
            f32x4 acc[4][4];
            #pragma unroll
            for (int i = 0; i < 4; ++i)
                #pragma unroll
                for (int j = 0; j < 4; ++j) acc[i][j] = (f32x4){0.f, 0.f, 0.f, 0.f};

            #pragma unroll
            for (int kt = 0; kt < 6; ++kt) {
                const int t = nc * 6 + kt;
                if (t < 40) {
                    // step t+2: chunk nn2, k-col nk2 (static per kt)
                    int nn2 = (kt < 4) ? nc : nc + 1;
                    int nk2 = ((kt + 2) % 6) * 32;
                    int g0 = nn2 * 128 + r0, g1 = nn2 * 128 + r1;
                    bR2[0] = (g0 < IN_DIM) ? *(const bfrag*)(Wt4 + (size_t)g0 * 192 + nk2 + s0 * 8) : zf;
                    bR2[1] = (g1 < IN_DIM) ? *(const bfrag*)(Wt4 + (size_t)g1 * 192 + nk2 + s0 * 8) : zf;
                }
                const unsigned short* B = Bs[t & 1];
                bfrag bf[4];
                #pragma unroll
                for (int j = 0; j < 4; ++j) bf[j] = *(const bfrag*)&B[brd4[j]];
                #pragma unroll
                for (int i = 0; i < 4; ++i)
                    #pragma unroll
                    for (int j = 0; j < 4; ++j)
                        acc[i][j] = __builtin_amdgcn_mfma_f32_16x16x32_bf16(af4[kt][i], bf[j], acc[i][j], 0, 0, 0);
                if (t < 41) {
                    unsigned short* Bn = Bs[(t + 1) & 1];
                    *(bfrag*)&Bn[bw0] = bR1[0];
                    *(bfrag*)&Bn[bw1] = bR1[1];
                    LBAR();
                    bR1[0] = bR2[0]; bR1[1] = bR2[1];
                }
            }

            float bv[4];
            #pragma unroll
            for (int j = 0; j < 4; ++j) {
                int nn = nc * 128 + wn * 64 + j * 16 + lr;
                bv[j] = (nn < IN_DIM) ? b4[nn] : 0.f;
            }
            #pragma unroll
            for (int i = 0; i < 4; ++i)
                #pragma unroll
                for (int j = 0; j < 4; ++j)
                    #pragma unroll
                    for (int r = 0; r < 4; ++r) {
                        int gm = m0 + wm * 64 + i * 16 + lk * 4 + r;
                        int nn = nc * 128 + wn * 64 + j * 16 + lr;
                        if (gm < M && nn < IN_DIM)
                            decoded[(size_t)gm * IN_DIM + nn] = acc[i][j][r] + bv[j];
                    }
        }
    }
}

// ---------------- launch ----------------

extern "C" void kernel_launch(void* const* d_in, const int* in_sizes, int n_in,
                              void* d_out, int out_size, void* d_ws, size_t ws_size,
                              hipStream_t stream) {
    const float* features = (const float*)d_in[0];
    const int*   src      = (const int*)d_in[1];
    const int*   dst      = (const int*)d_in[2];
    const float* W_enc1   = (const float*)d_in[3];
    const float* b_enc1   = (const float*)d_in[4];
    const float* W_enc3   = (const float*)d_in[5];
    const float* b_enc3   = (const float*)d_in[6];
    const float* W_dec1   = (const float*)d_in[7];
    const float* b_dec1   = (const float*)d_in[8];
    const float* W_dec3   = (const float*)d_in[9];
    const float* b_dec3   = (const float*)d_in[10];

    const int n = in_sizes[0] / NODELEN;  // 50000
    const int e = in_sizes[1];            // 200000

    // d_out layout: encoded [n,128] | decoded [n,788] | emb [n,788]
    float* encoded = (float*)d_out;
    float* decoded = encoded + (size_t)n * EMBDIM;
    float* emb     = decoded + (size_t)n * IN_DIM;

    // ws layout (bytes)
    char* ws = (char*)d_ws;
    unsigned short* h1    = (unsigned short*)(ws + 0);        // n*394*2 (reused by enc16)
    unsigned short* enc16 = (unsigned short*)(ws + 0);        // n*128*2 (after gathers)
    unsigned short* Wt1 = (unsigned short*)(ws + 40000000);
    unsigned short* Wt2 = (unsigned short*)(ws + 40400000);
    unsigned short* Wt3 = (unsigned short*)(ws + 40500000);
    unsigned short* Wt4 = (unsigned short*)(ws + 40600000);
    float* inv          = (float*)(ws + 41000000);
    int*   deg          = (int*)  (ws + 41200000);
    int*   rowstart     = (int*)  (ws + 41400000);
    int*   cursor       = (int*)  (ws + 41600000);
    int*   elist        = (int*)  (ws + 41800000);
    int*   bsum         = (int*)  (ws + 42600000);
    unsigned short* emb16 = (unsigned short*)(ws + 44000000); // n*800*2 = 80 MB
    const size_t NEED = 44000000ull + (size_t)n * 800 * 2;    // 124 MB
    const int useBF = (ws_size >= NEED) ? 1 : 0;

    const int nb = (n + 255) / 256;
    const int eb = (e + 255) / 256;
    const int total = n * NCHUNK;  // 9,850,000

    transpose_all<<<(T1E + T2E + T3E + T4E + 255) / 256, 256, 0, stream>>>(
        W_enc1, Wt1, W_enc3, Wt2, W_dec1, Wt3, W_dec3, Wt4);

    hipMemsetAsync(deg, 0, (size_t)n * sizeof(int), stream);
    count_deg<<<eb, 256, 0, stream>>>(dst, deg, e);
    block_sum<<<nb, 256, 0, stream>>>(deg, bsum, n);
    scan_bsums<<<1, 256, 0, stream>>>(bsum, nb);
    block_scan<<<nb, 256, 0, stream>>>(deg, bsum, rowstart, cursor, inv, n);
    fill_edges<<<eb, 256, 0, stream>>>(src, dst, cursor, elist, e);

    gather1<<<2048, 256, 0, stream>>>(features, rowstart, deg, inv, elist, h1, total);
    gather2_emb<<<2048, 256, 0, stream>>>(features, (const unsigned*)h1, rowstart, deg,
                                          inv, elist, emb,
                                          useBF ? (unsigned*)emb16 : nullptr, total);

    const int MB = (n + 127) / 128;  // 391 blocks
    if (useBF) {
        mlp12<1><<<MB, 256, 0, stream>>>(emb16, Wt1, Wt2, b_enc1, b_enc3, encoded, enc16, n);
    } else {
        mlp12<0><<<MB, 256, 0, stream>>>(emb, Wt1, Wt2, b_enc1, b_enc3, encoded, enc16, n);
    }
    mlp34<<<MB, 256, 0, stream>>>(enc16, Wt3, Wt4, b_dec1, b_dec3, decoded, n);
}

// Round 11
// 340.336 us; speedup vs baseline: 1.0883x; 1.0883x over previous
//
#include <hip/hip_runtime.h>
#include <hip/hip_bf16.h>

#define NODELEN 394
#define IN_DIM 788
#define H2DIM 192
#define EMBDIM 128
#define NCHUNK 197   // 394 elems = 197 x (float2 | uint-packed-bf16x2)

typedef __attribute__((ext_vector_type(4))) float f32x4;
typedef __attribute__((ext_vector_type(8))) short bfrag;  // 8 bf16 = 4 VGPRs

// raw barrier: LDS-coherent (ds_write completion tracked by lgkmcnt), does NOT
// drain vmcnt -- global prefetches stay in flight across the barrier.
#define LBAR() do { asm volatile("s_waitcnt lgkmcnt(0)" ::: "memory"); \
                    __builtin_amdgcn_s_barrier(); } while (0)

static __device__ __forceinline__ unsigned short f2bf(float f) {
    union { float f; unsigned u; } v; v.f = f;
    unsigned r = v.u + 0x7FFFu + ((v.u >> 16) & 1u);  // round-to-nearest-even
    return (unsigned short)(r >> 16);
}
static __device__ __forceinline__ float bf2f(unsigned short h) {
    union { unsigned u; float f; } v; v.u = ((unsigned)h) << 16;
    return v.f;
}
static __device__ __forceinline__ unsigned short f2bf_fast(float f) {
    __hip_bfloat16 h = __float2bfloat16(f);
    union { __hip_bfloat16 h; unsigned short u; } c; c.h = h; return c.u;
}

// ---------------- CSR build ----------------

__global__ void count_deg(const int* __restrict__ dst, int* __restrict__ deg, int e) {
    int i = blockIdx.x * blockDim.x + threadIdx.x;
    if (i < e) atomicAdd(&deg[dst[i]], 1);
}

__global__ void block_sum(const int* __restrict__ deg, int* __restrict__ bsum, int n) {
    __shared__ int s[256];
    int t = threadIdx.x;
    int i = blockIdx.x * 256 + t;
    s[t] = (i < n) ? deg[i] : 0;
    __syncthreads();
    for (int d = 128; d > 0; d >>= 1) {
        if (t < d) s[t] += s[t + d];
        __syncthreads();
    }
    if (t == 0) bsum[blockIdx.x] = s[0];
}

__global__ void scan_bsums(int* bsum, int nb) {
    __shared__ int s[256];
    int t = threadIdx.x;
    int x0 = (t < nb) ? bsum[t] : 0;
    s[t] = x0;
    __syncthreads();
    for (int d = 1; d < 256; d <<= 1) {
        int u = (t >= d) ? s[t - d] : 0;
        __syncthreads();
        s[t] += u;
        __syncthreads();
    }
    if (t < nb) bsum[t] = s[t] - x0;
}

__global__ void block_scan(const int* __restrict__ deg, const int* __restrict__ boff,
                           int* __restrict__ rowstart, int* __restrict__ cursor,
                           float* __restrict__ inv, int n) {
    __shared__ int s[256];
    int t = threadIdx.x;
    int i = blockIdx.x * 256 + t;
    int x0 = (i < n) ? deg[i] : 0;
    s[t] = x0;
    __syncthreads();
    for (int d = 1; d < 256; d <<= 1) {
        int u = (t >= d) ? s[t - d] : 0;
        __syncthreads();
        s[t] += u;
        __syncthreads();
    }
    if (i < n) {
        int r = boff[blockIdx.x] + s[t] - x0;
        rowstart[i] = r;
        cursor[i] = r;
        inv[i] = 1.0f / fmaxf((float)x0, 1.0f);
    }
}

__global__ void fill_edges(const int* __restrict__ src, const int* __restrict__ dst,
                           int* __restrict__ cursor, int* __restrict__ elist, int e) {
    int i = blockIdx.x * blockDim.x + threadIdx.x;
    if (i < e) {
        int p = atomicAdd(&cursor[dst[i]], 1);
        elist[p] = src[i];
    }
}

// ---------------- aggregation (gather, block-per-node: wave-uniform CSR reads) ----

__global__ __launch_bounds__(256) void gather1(
        const float* __restrict__ feat, const int* __restrict__ rowstart,
        const int* __restrict__ deg, const float* __restrict__ inv,
        const int* __restrict__ elist, unsigned short* __restrict__ h1) {
    const int node = blockIdx.x;
    const int c = threadIdx.x;
    if (c >= NCHUNK) return;
    const int beg = rowstart[node];
    const int dc = deg[node];
    const float s = inv[node];
    const size_t off = (size_t)c * 2;

    float ax = 0.f, ay = 0.f, bx = 0.f, by = 0.f;
    float cx = 0.f, cy = 0.f, dx = 0.f, dy = 0.f;
    int j = 0;
    for (; j + 3 < dc; j += 4) {
        int n0 = elist[beg + j], n1 = elist[beg + j + 1];
        int n2 = elist[beg + j + 2], n3 = elist[beg + j + 3];
        float2 v0 = *(const float2*)(feat + (size_t)n0 * NODELEN + off);
        float2 v1 = *(const float2*)(feat + (size_t)n1 * NODELEN + off);
        float2 v2 = *(const float2*)(feat + (size_t)n2 * NODELEN + off);
        float2 v3 = *(const float2*)(feat + (size_t)n3 * NODELEN + off);
        ax += v0.x; ay += v0.y; bx += v1.x; by += v1.y;
        cx += v2.x; cy += v2.y; dx += v3.x; dy += v3.y;
    }
    for (; j < dc; ++j) {
        int n0 = elist[beg + j];
        float2 v0 = *(const float2*)(feat + (size_t)n0 * NODELEN + off);
        ax += v0.x; ay += v0.y;
    }
    float fx = (ax + bx + cx + dx) * s;
    float fy = (ay + by + cy + dy) * s;
    if (c == 0) fx = 0.f;
    unsigned out = ((unsigned)f2bf(fy) << 16) | (unsigned)f2bf(fx);
    *(unsigned*)(h1 + (size_t)node * NODELEN + off) = out;
}

// emb fp32 [n][788]; optionally emb16 bf16 [n][800] (cols 788..799 zero)
__global__ __launch_bounds__(256) void gather2_emb(
        const float* __restrict__ feat, const unsigned* __restrict__ h1,
        const int* __restrict__ rowstart, const int* __restrict__ deg,
        const float* __restrict__ inv, const int* __restrict__ elist,
        float* __restrict__ emb, unsigned* __restrict__ emb16u) {
    const int node = blockIdx.x;
    const int c = threadIdx.x;
    if (c >= NCHUNK) return;
    const int beg = rowstart[node];
    const int dc = deg[node];
    const float s = inv[node];

    float ax = 0.f, ay = 0.f, bx = 0.f, by = 0.f;
    float cx = 0.f, cy = 0.f, dx = 0.f, dy = 0.f;
    int j = 0;
    for (; j + 3 < dc; j += 4) {
        int n0 = elist[beg + j], n1 = elist[beg + j + 1];
        int n2 = elist[beg + j + 2], n3 = elist[beg + j + 3];
        unsigned u0 = h1[(size_t)n0 * NCHUNK + c];
        unsigned u1 = h1[(size_t)n1 * NCHUNK + c];
        unsigned u2 = h1[(size_t)n2 * NCHUNK + c];
        unsigned u3 = h1[(size_t)n3 * NCHUNK + c];
        ax += bf2f((unsigned short)u0); ay += bf2f((unsigned short)(u0 >> 16));
        bx += bf2f((unsigned short)u1); by += bf2f((unsigned short)(u1 >> 16));
        cx += bf2f((unsigned short)u2); cy += bf2f((unsigned short)(u2 >> 16));
        dx += bf2f((unsigned short)u3); dy += bf2f((unsigned short)(u3 >> 16));
    }
    for (; j < dc; ++j) {
        int n0 = elist[beg + j];
        unsigned u0 = h1[(size_t)n0 * NCHUNK + c];
        ax += bf2f((unsigned short)u0); ay += bf2f((unsigned short)(u0 >> 16));
    }
    float hx = (ax + bx + cx + dx) * s;
    float hy = (ay + by + cy + dy) * s;

    const float* fr = feat + (size_t)node * NODELEN;
    float* er = emb + (size_t)node * IN_DIM;
    float2 fv = *(const float2*)(fr + c * 2);
    if (c == 0) { fv.x = 0.f; hx = 0.f; }
    *(float2*)(er + c * 2) = fv;
    float2 hv; hv.x = hx; hv.y = hy;
    *(float2*)(er + NODELEN + c * 2) = hv;

    if (emb16u) {
        unsigned* e16 = emb16u + (size_t)node * 400;
        e16[c]          = ((unsigned)f2bf(fv.y) << 16) | (unsigned)f2bf(fv.x);
        e16[NCHUNK + c] = ((unsigned)f2bf(hy)  << 16) | (unsigned)f2bf(hx);
        if (c < 6) e16[394 + c] = 0u;
    }
}

// ---------------- fused weight pre-transpose ----------
__device__ __forceinline__ void tr_one(const float* W, unsigned short* Wt,
                                       int K, int N, int Kp, int idx) {
    int nrow = idx / Kp, k = idx - nrow * Kp;
    Wt[idx] = (k < K) ? f2bf(W[(size_t)k * N + nrow]) : (unsigned short)0;
}

#define T1E (192 * 800)
#define T2E (128 * 192)
#define T3E (192 * 128)
#define T4E (788 * 192)

__global__ void transpose_all(const float* __restrict__ W1, unsigned short* __restrict__ Wt1,
                              const float* __restrict__ W2, unsigned short* __restrict__ Wt2,
                              const float* __restrict__ W3, unsigned short* __restrict__ Wt3,
                              const float* __restrict__ W4, unsigned short* __restrict__ Wt4) {
    int idx = blockIdx.x * 256 + threadIdx.x;
    if (idx < T1E) { tr_one(W1, Wt1, IN_DIM, H2DIM, 800, idx); return; }
    idx -= T1E;
    if (idx < T2E) { tr_one(W2, Wt2, H2DIM, EMBDIM, 192, idx); return; }
    idx -= T2E;
    if (idx < T3E) { tr_one(W3, Wt3, EMBDIM, H2DIM, 128, idx); return; }
    idx -= T3E;
    if (idx < T4E) { tr_one(W4, Wt4, H2DIM, IN_DIM, 192, idx); return; }
}

// ---------------- MLP kernels: BM=128, 2-deep prefetch pipeline ------------------
static __device__ __forceinline__ int bs_addr(int r, int s) {           // Bs[192][32]
    return r * 32 + ((s ^ ((r >> 1) & 3)) << 3);
}
static __device__ __forceinline__ int xy_base(int r, int s) {           // XY[128][192]
    int ph = (s & 24) | ((s ^ r) & 7);
    return r * 192 + (ph << 3);
}
static __device__ __forceinline__ int xy_addr_s(int r, int col) { return xy_base(r, col >> 3) + (col & 7); }

static __device__ __forceinline__ bfrag load_af_bf(const unsigned short* A800, int gm, int M, int col) {
    const bfrag zf = {0, 0, 0, 0, 0, 0, 0, 0};
    return (gm < M) ? *(const bfrag*)(A800 + (size_t)gm * 800 + col) : zf;
}
static __device__ __forceinline__ bfrag load_af_f32(const float* A, int gm, int M, int col) {
    float t[8];
    #pragma unroll
    for (int q = 0; q < 8; ++q) t[q] = 0.f;
    if (gm < M) {
        const float* rp = A + (size_t)gm * IN_DIM;
        if (col + 8 <= IN_DIM) {
            float4 v0 = *(const float4*)(rp + col), v1 = *(const float4*)(rp + col + 4);
            t[0] = v0.x; t[1] = v0.y; t[2] = v0.z; t[3] = v0.w;
            t[4] = v1.x; t[5] = v1.y; t[6] = v1.z; t[7] = v1.w;
        } else {
            #pragma unroll
            for (int q = 0; q < 8; ++q) if (col + q < IN_DIM) t[q] = rp[col + q];
        }
    }
    union { unsigned short u[8]; bfrag v; } pk;
    #pragma unroll
    for (int q = 0; q < 8; ++q) pk.u[q] = f2bf_fast(t[q]);
    return pk.v;
}

// ===== kernel A: stage1+2  emb -> x(lds) -> encoded(f32) + enc16(bf16) ==========
template <int ABF>
__global__ __launch_bounds__(256, 2) void mlp12(
    const void* __restrict__ Aemb,           // ABF ? bf16[n][800] : f32[n][788]
    const unsigned short* __restrict__ Wt1,  // [192][800]
    const unsigned short* __restrict__ Wt2,  // [128][192]
    const float* __restrict__ b1, const float* __restrict__ b2,
    float* __restrict__ encoded, unsigned short* __restrict__ enc16, int M)
{
    __shared__ unsigned short XY[128 * 192];     // 48 KB
    __shared__ unsigned short Bs[2][192 * 32];   // 24 KB

    const int tid = threadIdx.x;
    const int wid = tid >> 6, l = tid & 63;
    const int wm = wid >> 1, wn = wid & 1;       // 2x2 waves; wave tile 64 x 96
    const int lr = l & 15, lk = l >> 4;
    const int m0 = blockIdx.x * 128;

    const int r0 = tid >> 2, s0 = tid & 3;       // staging units
    const int r1 = r0 + 64, r2 = r0 + 128;
    const int bw0 = bs_addr(r0, s0);
    const int bw1 = bs_addr(r1, s0);
    const int bw2 = bs_addr(r2, s0);
    int brd6[6], brd4[4];
    #pragma unroll
    for (int j = 0; j < 6; ++j) brd6[j] = bs_addr(wn * 96 + j * 16 + lr, lk);
    #pragma unroll
    for (int j = 0; j < 4; ++j) brd4[j] = bs_addr(wn * 64 + j * 16 + lr, lk);

    int gmA[4];
    #pragma unroll
    for (int i = 0; i < 4; ++i) gmA[i] = m0 + wm * 64 + i * 16 + lr;

    // ---- STAGE 1: K=800 (25 steps), N=192, 2-deep prefetch ----
    {
        f32x4 acc[4][6];
        #pragma unroll
        for (int i = 0; i < 4; ++i)
            #pragma unroll
            for (int j = 0; j < 6; ++j) acc[i][j] = (f32x4){0.f, 0.f, 0.f, 0.f};

        bfrag afC[4], afN[4], afN2[4], bR1[3], bR2[3];
        #pragma unroll
        for (int i = 0; i < 4; ++i) {
            afC[i] = ABF ? load_af_bf((const unsigned short*)Aemb, gmA[i], M, lk * 8)
                         : load_af_f32((const float*)Aemb, gmA[i], M, lk * 8);
            afN[i] = ABF ? load_af_bf((const unsigned short*)Aemb, gmA[i], M, 32 + lk * 8)
                         : load_af_f32((const float*)Aemb, gmA[i], M, 32 + lk * 8);
        }
        // B(0) -> Bs[0]; B(1) -> regs
        *(bfrag*)&Bs[0][bw0] = *(const bfrag*)(Wt1 + (size_t)r0 * 800 + s0 * 8);
        *(bfrag*)&Bs[0][bw1] = *(const bfrag*)(Wt1 + (size_t)r1 * 800 + s0 * 8);
        *(bfrag*)&Bs[0][bw2] = *(const bfrag*)(Wt1 + (size_t)r2 * 800 + s0 * 8);
        bR1[0] = *(const bfrag*)(Wt1 + (size_t)r0 * 800 + 32 + s0 * 8);
        bR1[1] = *(const bfrag*)(Wt1 + (size_t)r1 * 800 + 32 + s0 * 8);
        bR1[2] = *(const bfrag*)(Wt1 + (size_t)r2 * 800 + 32 + s0 * 8);
        LBAR();

        #pragma unroll 5
        for (int kt = 0; kt < 25; ++kt) {
            if (kt < 23) {
                int k2 = (kt + 2) * 32;
                #pragma unroll
                for (int i = 0; i < 4; ++i)
                    afN2[i] = ABF ? load_af_bf((const unsigned short*)Aemb, gmA[i], M, k2 + lk * 8)
                                  : load_af_f32((const float*)Aemb, gmA[i], M, k2 + lk * 8);
                bR2[0] = *(const bfrag*)(Wt1 + (size_t)r0 * 800 + k2 + s0 * 8);
                bR2[1] = *(const bfrag*)(Wt1 + (size_t)r1 * 800 + k2 + s0 * 8);
                bR2[2] = *(const bfrag*)(Wt1 + (size_t)r2 * 800 + k2 + s0 * 8);
            }
            const unsigned short* B = Bs[kt & 1];
            bfrag bf[6];
            #pragma unroll
            for (int j = 0; j < 6; ++j) bf[j] = *(const bfrag*)&B[brd6[j]];
            #pragma unroll
            for (int i = 0; i < 4; ++i)
                #pragma unroll
                for (int j = 0; j < 6; ++j)
                    acc[i][j] = __builtin_amdgcn_mfma_f32_16x16x32_bf16(afC[i], bf[j], acc[i][j], 0, 0, 0);
            if (kt < 24) {
                unsigned short* Bn = Bs[(kt + 1) & 1];
                *(bfrag*)&Bn[bw0] = bR1[0];
                *(bfrag*)&Bn[bw1] = bR1[1];
                *(bfrag*)&Bn[bw2] = bR1[2];
                LBAR();
                #pragma unroll
                for (int i = 0; i < 4; ++i) { afC[i] = afN[i]; afN[i] = afN2[i]; }
                bR1[0] = bR2[0]; bR1[1] = bR2[1]; bR1[2] = bR2[2];
            }
        }
        float bv[6];
        #pragma unroll
        for (int j = 0; j < 6; ++j) bv[j] = b1[wn * 96 + j * 16 + lr];
        #pragma unroll
        for (int i = 0; i < 4; ++i)
            #pragma unroll
            for (int j = 0; j < 6; ++j)
                #pragma unroll
                for (int r = 0; r < 4; ++r) {
                    int m = wm * 64 + i * 16 + lk * 4 + r;
                    int n1 = wn * 96 + j * 16 + lr;
                    XY[xy_addr_s(m, n1)] = f2bf_fast(fmaxf(acc[i][j][r] + bv[j], 0.f));
                }
    }
    __syncthreads();   // x visible, stage-1 Bs reads done

    // ---- STAGE 2: K=192 (6 steps), N=128, 2-deep B ----
    {
        f32x4 acc[4][4];
        #pragma unroll
        for (int i = 0; i < 4; ++i)
            #pragma unroll
            for (int j = 0; j < 4; ++j) acc[i][j] = (f32x4){0.f, 0.f, 0.f, 0.f};

        bfrag bR1[2], bR2[2];
        *(bfrag*)&Bs[0][bw0] = *(const bfrag*)(Wt2 + (size_t)r0 * 192 + s0 * 8);
        *(bfrag*)&Bs[0][bw1] = *(const bfrag*)(Wt2 + (size_t)r1 * 192 + s0 * 8);
        bR1[0] = *(const bfrag*)(Wt2 + (size_t)r0 * 192 + 32 + s0 * 8);
        bR1[1] = *(const bfrag*)(Wt2 + (size_t)r1 * 192 + 32 + s0 * 8);
        LBAR();

        #pragma unroll
        for (int kt = 0; kt < 6; ++kt) {
            if (kt < 4) {
                int k2 = (kt + 2) * 32;
                bR2[0] = *(const bfrag*)(Wt2 + (size_t)r0 * 192 + k2 + s0 * 8);
                bR2[1] = *(const bfrag*)(Wt2 + (size_t)r1 * 192 + k2 + s0 * 8);
            }
            const unsigned short* B = Bs[kt & 1];
            bfrag af[4], bf[4];
            #pragma unroll
            for (int i = 0; i < 4; ++i)
                af[i] = *(const bfrag*)&XY[xy_base(wm * 64 + i * 16 + lr, kt * 4 + lk)];
            #pragma unroll
            for (int j = 0; j < 4; ++j) bf[j] = *(const bfrag*)&B[brd4[j]];
            #pragma unroll
            for (int i = 0; i < 4; ++i)
                #pragma unroll
                for (int j = 0; j < 4; ++j)
                    acc[i][j] = __builtin_amdgcn_mfma_f32_16x16x32_bf16(af[i], bf[j], acc[i][j], 0, 0, 0);
            if (kt < 5) {
                unsigned short* Bn = Bs[(kt + 1) & 1];
                *(bfrag*)&Bn[bw0] = bR1[0];
                *(bfrag*)&Bn[bw1] = bR1[1];
                LBAR();
                bR1[0] = bR2[0]; bR1[1] = bR2[1];
            }
        }

        float bv[4];
        #pragma unroll
        for (int j = 0; j < 4; ++j) bv[j] = b2[wn * 64 + j * 16 + lr];
        #pragma unroll
        for (int i = 0; i < 4; ++i)
            #pragma unroll
            for (int j = 0; j < 4; ++j)
                #pragma unroll
                for (int r = 0; r < 4; ++r) {
                    int m = wm * 64 + i * 16 + lk * 4 + r;
                    int nn = wn * 64 + j * 16 + lr;
                    float v = acc[i][j][r] + bv[j];
                    int gm = m0 + m;
                    if (gm < M) {
                        encoded[(size_t)gm * EMBDIM + nn] = v;
                        enc16[(size_t)gm * EMBDIM + nn] = f2bf_fast(v);
                    }
                }
    }
}

// ===== kernel B: stage3+4  enc16 -> y(lds) -> decoded(f32) ======================
__global__ __launch_bounds__(256, 2) void mlp34(
    const unsigned short* __restrict__ enc16,
    const unsigned short* __restrict__ Wt3,  // [192][128]
    const unsigned short* __restrict__ Wt4,  // [788][192]
    const float* __restrict__ b3, const float* __restrict__ b4,
    float* __restrict__ decoded, int M)
{
    __shared__ unsigned short XY[128 * 192];     // 48 KB (y)
    __shared__ unsigned short Bs[2][192 * 32];   // 24 KB

    const int tid = threadIdx.x;
    const int wid = tid >> 6, l = tid & 63;
    const int wm = wid >> 1, wn = wid & 1;
    const int lr = l & 15, lk = l >> 4;
    const int m0 = blockIdx.x * 128;
    const bfrag zf = {0, 0, 0, 0, 0, 0, 0, 0};

    const int r0 = tid >> 2, s0 = tid & 3;
    const int r1 = r0 + 64, r2 = r0 + 128;
    const int bw0 = bs_addr(r0, s0);
    const int bw1 = bs_addr(r1, s0);
    const int bw2 = bs_addr(r2, s0);
    int brd6[6], brd4[4];
    #pragma unroll
    for (int j = 0; j < 6; ++j) brd6[j] = bs_addr(wn * 96 + j * 16 + lr, lk);
    #pragma unroll
    for (int j = 0; j < 4; ++j) brd4[j] = bs_addr(wn * 64 + j * 16 + lr, lk);

    int gmA[4];
    #pragma unroll
    for (int i = 0; i < 4; ++i) gmA[i] = m0 + wm * 64 + i * 16 + lr;

    // ---- STAGE 3: y = relu(enc @ W3 + b3), K=128 (4 steps), N=192, 2-deep ----
    {
        f32x4 acc[4][6];
        #pragma unroll
        for (int i = 0; i < 4; ++i)
            #pragma unroll
            for (int j = 0; j < 6; ++j) acc[i][j] = (f32x4){0.f, 0.f, 0.f, 0.f};

        bfrag afC[4], afN[4], afN2[4], bR1[3], bR2[3];
        #pragma unroll
        for (int i = 0; i < 4; ++i) {
            afC[i] = (gmA[i] < M) ? *(const bfrag*)(enc16 + (size_t)gmA[i] * EMBDIM + lk * 8) : zf;
            afN[i] = (gmA[i] < M) ? *(const bfrag*)(enc16 + (size_t)gmA[i] * EMBDIM + 32 + lk * 8) : zf;
        }
        *(bfrag*)&Bs[0][bw0] = *(const bfrag*)(Wt3 + (size_t)r0 * 128 + s0 * 8);
        *(bfrag*)&Bs[0][bw1] = *(const bfrag*)(Wt3 + (size_t)r1 * 128 + s0 * 8);
        *(bfrag*)&Bs[0][bw2] = *(const bfrag*)(Wt3 + (size_t)r2 * 128 + s0 * 8);
        bR1[0] = *(const bfrag*)(Wt3 + (size_t)r0 * 128 + 32 + s0 * 8);
        bR1[1] = *(const bfrag*)(Wt3 + (size_t)r1 * 128 + 32 + s0 * 8);
        bR1[2] = *(const bfrag*)(Wt3 + (size_t)r2 * 128 + 32 + s0 * 8);
        LBAR();

        #pragma unroll
        for (int kt = 0; kt < 4; ++kt) {
            if (kt < 2) {
                int k2 = (kt + 2) * 32;
                #pragma unroll
                for (int i = 0; i < 4; ++i)
                    afN2[i] = (gmA[i] < M)
                        ? *(const bfrag*)(enc16 + (size_t)gmA[i] * EMBDIM + k2 + lk * 8) : zf;
                bR2[0] = *(const bfrag*)(Wt3 + (size_t)r0 * 128 + k2 + s0 * 8);
                bR2[1] = *(const bfrag*)(Wt3 + (size_t)r1 * 128 + k2 + s0 * 8);
                bR2[2] = *(const bfrag*)(Wt3 + (size_t)r2 * 128 + k2 + s0 * 8);
            }
            const unsigned short* B = Bs[kt & 1];
            bfrag bf[6];
            #pragma unroll
            for (int j = 0; j < 6; ++j) bf[j] = *(const bfrag*)&B[brd6[j]];
            #pragma unroll
            for (int i = 0; i < 4; ++i)
                #pragma unroll
                for (int j = 0; j < 6; ++j)
                    acc[i][j] = __builtin_amdgcn_mfma_f32_16x16x32_bf16(afC[i], bf[j], acc[i][j], 0, 0, 0);
            if (kt < 3) {
                unsigned short* Bn = Bs[(kt + 1) & 1];
                *(bfrag*)&Bn[bw0] = bR1[0];
                *(bfrag*)&Bn[bw1] = bR1[1];
                *(bfrag*)&Bn[bw2] = bR1[2];
                LBAR();
                #pragma unroll
                for (int i = 0; i < 4; ++i) { afC[i] = afN[i]; afN[i] = afN2[i]; }
                bR1[0] = bR2[0]; bR1[1] = bR2[1]; bR1[2] = bR2[2];
            }
        }

        float bv[6];
        #pragma unroll
        for (int j = 0; j < 6; ++j) bv[j] = b3[wn * 96 + j * 16 + lr];
        #pragma unroll
        for (int i = 0; i < 4; ++i)
            #pragma unroll
            for (int j = 0; j < 6; ++j)
                #pragma unroll
                for (int r = 0; r < 4; ++r) {
                    int m = wm * 64 + i * 16 + lk * 4 + r;
                    int nc = wn * 96 + j * 16 + lr;
                    XY[xy_addr_s(m, nc)] = f2bf_fast(fmaxf(acc[i][j][r] + bv[j], 0.f));
                }
    }
    __syncthreads();   // y visible

    // ---- STAGE 4: dec = y @ W4 + b4, K=192 (6 steps), N=788 (7 x 128), 2-deep ----
    {
        bfrag af4[6][4];   // hoisted once, reused across chunks
        #pragma unroll
        for (int q = 0; q < 6; ++q)
            #pragma unroll
            for (int i = 0; i < 4; ++i)
                af4[q][i] = *(const bfrag*)&XY[xy_base(wm * 64 + i * 16 + lr, q * 4 + lk)];

        bfrag bR1[2], bR2[2];
        // t=0 -> Bs[0]; t=1 -> regs (rows < 788 for chunk 0)
        *(bfrag*)&Bs[0][bw0] = *(const bfrag*)(Wt4 + (size_t)r0 * 192 + s0 * 8);
        *(bfrag*)&Bs[0][bw1] = *(const bfrag*)(Wt4 + (size_t)r1 * 192 + s0 * 8);
        bR1[0] = *(const bfrag*)(Wt4 + (size_t)r0 * 192 + 32 + s0 * 8);
        bR1[1] = *(const bfrag*)(Wt4 + (size_t)r1 * 192 + 32 + s0 * 8);
        LBAR();

        for (int nc = 0; nc < 7; ++nc) {
            f32x4 acc[4][4];
            #pragma unroll
            for (int i = 0; i < 4; ++i)
                #pragma unroll
                for (int j = 0; j < 4; ++j) acc[i][j] = (f32x4){0.f, 0.f, 0.f, 0.f};

            #pragma unroll
            for (int kt = 0; kt < 6; ++kt) {
                const int t = nc * 6 + kt;
                if (t < 40) {
                    // step t+2: chunk nn2, k-col nk2 (static per kt)
                    int nn2 = (kt < 4) ? nc : nc + 1;
                    int nk2 = ((kt + 2) % 6) * 32;
                    int g0 = nn2 * 128 + r0, g1 = nn2 * 128 + r1;
                    bR2[0] = (g0 < IN_DIM) ? *(const bfrag*)(Wt4 + (size_t)g0 * 192 + nk2 + s0 * 8) : zf;
                    bR2[1] = (g1 < IN_DIM) ? *(const bfrag*)(Wt4 + (size_t)g1 * 192 + nk2 + s0 * 8) : zf;
                }
                const unsigned short* B = Bs[t & 1];
                bfrag bf[4];
                #pragma unroll
                for (int j = 0; j < 4; ++j) bf[j] = *(const bfrag*)&B[brd4[j]];
                #pragma unroll
                for (int i = 0; i < 4; ++i)
                    #pragma unroll
                    for (int j = 0; j < 4; ++j)
                        acc[i][j] = __builtin_amdgcn_mfma_f32_16x16x32_bf16(af4[kt][i], bf[j], acc[i][j], 0, 0, 0);
                if (t < 41) {
                    unsigned short* Bn = Bs[(t + 1) & 1];
                    *(bfrag*)&Bn[bw0] = bR1[0];
                    *(bfrag*)&Bn[bw1] = bR1[1];
                    LBAR();
                    bR1[0] = bR2[0]; bR1[1] = bR2[1];
                }
            }

            float bv[4];
            #pragma unroll
            for (int j = 0; j < 4; ++j) {
                int nn = nc * 128 + wn * 64 + j * 16 + lr;
                bv[j] = (nn < IN_DIM) ? b4[nn] : 0.f;
            }
            #pragma unroll
            for (int i = 0; i < 4; ++i)
                #pragma unroll
                for (int j = 0; j < 4; ++j)
                    #pragma unroll
                    for (int r = 0; r < 4; ++r) {
                        int gm = m0 + wm * 64 + i * 16 + lk * 4 + r;
                        int nn = nc * 128 + wn * 64 + j * 16 + lr;
                        if (gm < M && nn < IN_DIM)
                            decoded[(size_t)gm * IN_DIM + nn] = acc[i][j][r] + bv[j];
                    }
        }
    }
}

// ---------------- launch ----------------

extern "C" void kernel_launch(void* const* d_in, const int* in_sizes, int n_in,
                              void* d_out, int out_size, void* d_ws, size_t ws_size,
                              hipStream_t stream) {
    const float* features = (const float*)d_in[0];
    const int*   src      = (const int*)d_in[1];
    const int*   dst      = (const int*)d_in[2];
    const float* W_enc1   = (const float*)d_in[3];
    const float* b_enc1   = (const float*)d_in[4];
    const float* W_enc3   = (const float*)d_in[5];
    const float* b_enc3   = (const float*)d_in[6];
    const float* W_dec1   = (const float*)d_in[7];
    const float* b_dec1   = (const float*)d_in[8];
    const float* W_dec3   = (const float*)d_in[9];
    const float* b_dec3   = (const float*)d_in[10];

    const int n = in_sizes[0] / NODELEN;  // 50000
    const int e = in_sizes[1];            // 200000

    // d_out layout: encoded [n,128] | decoded [n,788] | emb [n,788]
    float* encoded = (float*)d_out;
    float* decoded = encoded + (size_t)n * EMBDIM;
    float* emb     = decoded + (size_t)n * IN_DIM;

    // ws layout (bytes)
    char* ws = (char*)d_ws;
    unsigned short* h1    = (unsigned short*)(ws + 0);        // n*394*2 (reused by enc16)
    unsigned short* enc16 = (unsigned short*)(ws + 0);        // n*128*2 (after gathers)
    unsigned short* Wt1 = (unsigned short*)(ws + 40000000);
    unsigned short* Wt2 = (unsigned short*)(ws + 40400000);
    unsigned short* Wt3 = (unsigned short*)(ws + 40500000);
    unsigned short* Wt4 = (unsigned short*)(ws + 40600000);
    float* inv          = (float*)(ws + 41000000);
    int*   deg          = (int*)  (ws + 41200000);
    int*   rowstart     = (int*)  (ws + 41400000);
    int*   cursor       = (int*)  (ws + 41600000);
    int*   elist        = (int*)  (ws + 41800000);
    int*   bsum         = (int*)  (ws + 42600000);
    unsigned short* emb16 = (unsigned short*)(ws + 44000000); // n*800*2 = 80 MB
    const size_t NEED = 44000000ull + (size_t)n * 800 * 2;    // 124 MB
    const int useBF = (ws_size >= NEED) ? 1 : 0;

    const int nb = (n + 255) / 256;
    const int eb = (e + 255) / 256;

    transpose_all<<<(T1E + T2E + T3E + T4E + 255) / 256, 256, 0, stream>>>(
        W_enc1, Wt1, W_enc3, Wt2, W_dec1, Wt3, W_dec3, Wt4);

    hipMemsetAsync(deg, 0, (size_t)n * sizeof(int), stream);
    count_deg<<<eb, 256, 0, stream>>>(dst, deg, e);
    block_sum<<<nb, 256, 0, stream>>>(deg, bsum, n);
    scan_bsums<<<1, 256, 0, stream>>>(bsum, nb);
    block_scan<<<nb, 256, 0, stream>>>(deg, bsum, rowstart, cursor, inv, n);
    fill_edges<<<eb, 256, 0, stream>>>(src, dst, cursor, elist, e);

    gather1<<<n, 256, 0, stream>>>(features, rowstart, deg, inv, elist, h1);
    gather2_emb<<<n, 256, 0, stream>>>(features, (const unsigned*)h1, rowstart, deg,
                                       inv, elist, emb,
                                       useBF ? (unsigned*)emb16 : nullptr);

    const int MB = (n + 127) / 128;  // 391 blocks
    if (useBF) {
        mlp12<1><<<MB, 256, 0, stream>>>(emb16, Wt1, Wt2, b_enc1, b_enc3, encoded, enc16, n);
    } else {
        mlp12<0><<<MB, 256, 0, stream>>>(emb, Wt1, Wt2, b_enc1, b_enc3, encoded, enc16, n);
    }
    mlp34<<<MB, 256, 0, stream>>>(enc16, Wt3, Wt4, b_dec1, b_dec3, decoded, n);
}